// Round 1
// baseline (12342.374 us; speedup 1.0000x reference)
//
#include <hip/hip_runtime.h>
#include <hip/hip_bf16.h>

#define NSWEEP 8

static constexpr int NAP = 128;
static constexpr int NU  = 128;
static constexpr int F_  = 10;
static constexpr int BF  = 640;   // B*F
static constexpr int HID = 100;

// ---------------- Kernel 1: Gram + parallel Jacobi eigensolver + sort ------
__global__ __launch_bounds__(512)
void eig_kernel(const float* __restrict__ Ain,
                float* __restrict__ e_out,            // [BF][128]
                float* __restrict__ s_out,            // [BF][128]
                __hip_bfloat16* __restrict__ V_out)   // [BF][128][128]
{
    extern __shared__ float lds[];
    float* Lm = lds;               // [128][129]
    float* Vm = lds + 128 * 129;   // [128][129]
    __shared__ float c_sh[64];
    __shared__ float s_sh[64];
    __shared__ int   p_sh[64];
    __shared__ int   q_sh[64];
    __shared__ float key[128];
    __shared__ int   idxs[128];

    const int m   = blockIdx.x;
    const int bb  = m / F_;
    const int ff  = m % F_;
    const int tid = threadIdx.x;

    // ---- stage A[k][i] = Ain[bb][k][i][ff] into Vm region ----
    {
        const float* Ab = Ain + (size_t)bb * NAP * NU * F_ + ff;
        for (int t = tid; t < 128 * 128; t += 512) {
            Vm[(t >> 7) * 129 + (t & 127)] = Ab[(size_t)t * F_];
        }
    }
    __syncthreads();

    // ---- Gram: Lm[i][j] = sum_k A[k][i] * A[k][j] ----
    {
        const int tx = tid & 15;    // j tile (8 wide)
        const int ty = tid >> 4;    // i tile (4 tall), 0..31
        const int i0 = ty * 4, j0 = tx * 8;
        float acc[4][8];
        #pragma unroll
        for (int a = 0; a < 4; ++a)
            #pragma unroll
            for (int c = 0; c < 8; ++c) acc[a][c] = 0.f;
        for (int k = 0; k < 128; ++k) {
            float av[4], bv[8];
            #pragma unroll
            for (int a = 0; a < 4; ++a) av[a] = Vm[k * 129 + i0 + a];
            #pragma unroll
            for (int c = 0; c < 8; ++c) bv[c] = Vm[k * 129 + j0 + c];
            #pragma unroll
            for (int a = 0; a < 4; ++a)
                #pragma unroll
                for (int c = 0; c < 8; ++c) acc[a][c] += av[a] * bv[c];
        }
        #pragma unroll
        for (int a = 0; a < 4; ++a)
            #pragma unroll
            for (int c = 0; c < 8; ++c)
                Lm[(i0 + a) * 129 + j0 + c] = acc[a][c];
    }
    __syncthreads();

    // ---- V = I (overwrites A staging) ----
    for (int t = tid; t < 128 * 128; t += 512) {
        const int i = t >> 7, j = t & 127;
        Vm[i * 129 + j] = (i == j) ? 1.f : 0.f;
    }
    __syncthreads();

    // ---- parallel cyclic Jacobi: 127 rounds/sweep, 64 disjoint pairs/round
    for (int sw = 0; sw < NSWEEP; ++sw) {
        for (int r = 0; r < 127; ++r) {
            if (tid < 64) {
                int g = tid, p, q;
                if (g == 0) { p = r; q = 127; }
                else {
                    p = (r + g) % 127;
                    q = (r - g + 127) % 127;
                    if (p > q) { int t2 = p; p = q; q = t2; }
                }
                const float app = Lm[p * 129 + p];
                const float aqq = Lm[q * 129 + q];
                const float apq = Lm[p * 129 + q];
                float c = 1.f, s = 0.f;
                if (apq != 0.f) {
                    const float tau = (aqq - app) / (2.f * apq);
                    float t3 = 1.f / (fabsf(tau) + sqrtf(1.f + tau * tau));
                    if (tau < 0.f) t3 = -t3;
                    c = 1.f / sqrtf(1.f + t3 * t3);
                    s = t3 * c;
                }
                c_sh[g] = c; s_sh[g] = s; p_sh[g] = p; q_sh[g] = q;
            }
            __syncthreads();
            // row phase: rows p,q  (lanes contiguous in j -> conflict-free)
            {
                const int j = tid & 127;
                #pragma unroll
                for (int gg = 0; gg < 16; ++gg) {
                    const int g = (tid >> 7) + (gg << 2);
                    const int p = p_sh[g], q = q_sh[g];
                    const float c = c_sh[g], s = s_sh[g];
                    const float ap = Lm[p * 129 + j], aq = Lm[q * 129 + j];
                    Lm[p * 129 + j] = c * ap - s * aq;
                    Lm[q * 129 + j] = s * ap + c * aq;
                }
            }
            __syncthreads();
            // column phase + V accumulate (lanes contiguous in i, stride 129)
            {
                const int i = tid & 127;
                #pragma unroll
                for (int gg = 0; gg < 16; ++gg) {
                    const int g = (tid >> 7) + (gg << 2);
                    const int p = p_sh[g], q = q_sh[g];
                    const float c = c_sh[g], s = s_sh[g];
                    const float ap = Lm[i * 129 + p], aq = Lm[i * 129 + q];
                    Lm[i * 129 + p] = c * ap - s * aq;
                    Lm[i * 129 + q] = s * ap + c * aq;
                    const float vp = Vm[i * 129 + p], vq = Vm[i * 129 + q];
                    Vm[i * 129 + p] = c * vp - s * vq;
                    Vm[i * 129 + q] = s * vp + c * vq;
                }
            }
            __syncthreads();
        }
    }

    // ---- sort eigenpairs ascending (bitonic on 128 keys + index payload)
    if (tid < 128) { key[tid] = Lm[tid * 129 + tid]; idxs[tid] = tid; }
    __syncthreads();
    for (int kk = 2; kk <= 128; kk <<= 1) {
        for (int jj = kk >> 1; jj > 0; jj >>= 1) {
            if (tid < 128) {
                const int i = tid, l = i ^ jj;
                if (l > i) {
                    const bool up = ((i & kk) == 0);
                    const float ki = key[i], kl = key[l];
                    if ((ki > kl) == up) {
                        const int ii = idxs[i], il = idxs[l];
                        key[i] = kl; key[l] = ki;
                        idxs[i] = il; idxs[l] = ii;
                    }
                }
            }
            __syncthreads();
        }
    }

    // ---- outputs: e, s = colsum(V)/128 (sorted order), V as bf16 ----
    if (tid < 128) {
        e_out[(size_t)m * 128 + tid] = key[tid];
        const int pj = idxs[tid];
        float sum = 0.f;
        for (int i = 0; i < 128; ++i) sum += Vm[i * 129 + pj];
        s_out[(size_t)m * 128 + tid] = sum * (1.f / 128.f);
    }
    for (int t = tid; t < 128 * 128; t += 512) {
        const int i = t >> 7, j = t & 127;
        V_out[(size_t)m * 16384 + t] = __float2bfloat16(Vm[i * 129 + idxs[j]]);
    }
}

// ---------------- Kernel 2: MLP on eigenvalues (128 -> 100 -> 100) --------
__global__ __launch_bounds__(128)
void mlp_kernel(const float* __restrict__ e_in,   // [BF][128]
                const float* __restrict__ W0,     // [128][100]
                const float* __restrict__ b0,
                const float* __restrict__ W1,     // [100][100]
                const float* __restrict__ b1,
                float* __restrict__ y_out)        // [BF][100]
{
    __shared__ float ein[128];
    __shared__ float h0[HID];
    const int m = blockIdx.x;
    const int tid = threadIdx.x;
    ein[tid] = e_in[(size_t)m * 128 + tid];
    __syncthreads();
    if (tid < HID) {
        float a = b0[tid];
        for (int i = 0; i < 128; ++i) a += ein[i] * W0[i * HID + tid];
        h0[tid] = fmaxf(a, 0.f);
    }
    __syncthreads();
    if (tid < HID) {
        float a = b1[tid];
        for (int h = 0; h < HID; ++h) a += h0[h] * W1[h * HID + tid];
        y_out[(size_t)m * HID + tid] = fmaxf(a, 0.f);
    }
}

// ---------------- Kernel 3: D = Ysub@W2blk + b2; Out = (D*s)@V^T; exp -----
__global__ __launch_bounds__(256)
void final_kernel(const float* __restrict__ y,     // [BF][100]
                  const float* __restrict__ W2,    // [100][16384]
                  const float* __restrict__ b2,    // [16384]
                  const float* __restrict__ s_in,  // [BF][128]
                  const __hip_bfloat16* __restrict__ V_in, // [BF][128][128]
                  float* __restrict__ outp)        // [BF][128][128]
{
    extern __shared__ float lds[];
    float* Vs  = lds;            // [128][129] (filled in phase 2)
    float* Wm  = lds + 16512;    // [128][129]
    float* Ys  = lds;            // [128][101] staging (overlaps Vs)
    float* W2s = lds + 12928;    // [100][128] staging (overlaps Vs/Wm)

    const int m    = blockIdx.x;
    const int m_hi = m >> 7, m_lo = m & 127;
    const int tid  = threadIdx.x;
    const int tx   = tid & 15, ty = tid >> 4;

    // stage Y_sub rows (5t+m_hi) and the W2 column block m_lo*128..+127
    for (int u = tid; u < 128 * 100; u += 256) {
        const int t = u / 100, h = u - t * 100;
        Ys[t * 101 + h] = y[(size_t)(5 * t + m_hi) * 100 + h];
    }
    for (int u = tid; u < 100 * 128; u += 256) {
        const int h = u >> 7, c = u & 127;
        W2s[h * 128 + c] = W2[(size_t)h * 16384 + (size_t)m_lo * 128 + c];
    }
    __syncthreads();

    // D[t][u] = sum_h Ys[t][h]*W2s[h][u]; thread owns rows ty+16a, cols tx+16c
    float acc[8][8];
    #pragma unroll
    for (int a = 0; a < 8; ++a)
        #pragma unroll
        for (int c = 0; c < 8; ++c) acc[a][c] = 0.f;
    for (int h = 0; h < 100; ++h) {
        float yv[8], wv[8];
        #pragma unroll
        for (int a = 0; a < 8; ++a) yv[a] = Ys[(ty + 16 * a) * 101 + h];
        #pragma unroll
        for (int c = 0; c < 8; ++c) wv[c] = W2s[h * 128 + tx + 16 * c];
        #pragma unroll
        for (int a = 0; a < 8; ++a)
            #pragma unroll
            for (int c = 0; c < 8; ++c) acc[a][c] += yv[a] * wv[c];
    }
    {
        float b2v[8], sv[8];
        #pragma unroll
        for (int c = 0; c < 8; ++c) {
            b2v[c] = b2[m_lo * 128 + tx + 16 * c];
            sv[c]  = s_in[(size_t)m * 128 + tx + 16 * c];
        }
        #pragma unroll
        for (int a = 0; a < 8; ++a)
            #pragma unroll
            for (int c = 0; c < 8; ++c)
                acc[a][c] = (acc[a][c] + b2v[c]) * sv[c];
    }
    __syncthreads();   // staging dead

    // store W = D*s into Wm; load V (bf16 -> fp32) into Vs
    #pragma unroll
    for (int a = 0; a < 8; ++a)
        #pragma unroll
        for (int c = 0; c < 8; ++c)
            Wm[(ty + 16 * a) * 129 + tx + 16 * c] = acc[a][c];
    for (int u = tid; u < 16384; u += 256) {
        const int i = u >> 7, j = u & 127;
        Vs[i * 129 + j] = __bfloat162float(V_in[(size_t)m * 16384 + u]);
    }
    __syncthreads();

    // Out[t][i] = sum_j Wm[t][j] * Vs[i][j]; write exp()
    float o[8][8];
    #pragma unroll
    for (int a = 0; a < 8; ++a)
        #pragma unroll
        for (int c = 0; c < 8; ++c) o[a][c] = 0.f;
    for (int j = 0; j < 128; ++j) {
        float wv[8], vv[8];
        #pragma unroll
        for (int a = 0; a < 8; ++a) wv[a] = Wm[(ty + 16 * a) * 129 + j];
        #pragma unroll
        for (int c = 0; c < 8; ++c) vv[c] = Vs[(tx + 16 * c) * 129 + j];
        #pragma unroll
        for (int a = 0; a < 8; ++a)
            #pragma unroll
            for (int c = 0; c < 8; ++c) o[a][c] += wv[a] * vv[c];
    }
    #pragma unroll
    for (int a = 0; a < 8; ++a) {
        const int t = ty + 16 * a;
        const size_t rowbase = (size_t)(5 * t + m_hi) * 16384 + (size_t)m_lo * 128;
        #pragma unroll
        for (int c = 0; c < 8; ++c)
            outp[rowbase + tx + 16 * c] = expf(o[a][c]);
    }
}

// ---------------------------------------------------------------------------
extern "C" void kernel_launch(void* const* d_in, const int* in_sizes, int n_in,
                              void* d_out, int out_size, void* d_ws, size_t ws_size,
                              hipStream_t stream)
{
    const float* Ain = (const float*)d_in[0];
    const float* W0  = (const float*)d_in[1];
    const float* b0  = (const float*)d_in[2];
    const float* W1  = (const float*)d_in[3];
    const float* b1  = (const float*)d_in[4];
    const float* W2  = (const float*)d_in[5];
    const float* b2  = (const float*)d_in[6];
    float* outp = (float*)d_out;

    char* ws = (char*)d_ws;
    __hip_bfloat16* Vbf = (__hip_bfloat16*)ws;               // 640*16384*2 = 20971520 B
    float* e_ws = (float*)(ws + 20971520);                   // 640*128*4
    float* s_ws = (float*)(ws + 20971520 + 327680);          // 640*128*4
    float* y_ws = (float*)(ws + 20971520 + 655360);          // 640*100*4

    const size_t lds_bytes = (size_t)(2 * 128 * 129) * sizeof(float); // 132096

    eig_kernel<<<dim3(BF), dim3(512), lds_bytes, stream>>>(Ain, e_ws, s_ws, Vbf);
    mlp_kernel<<<dim3(BF), dim3(128), 0, stream>>>(e_ws, W0, b0, W1, b1, y_ws);
    final_kernel<<<dim3(BF), dim3(256), lds_bytes, stream>>>(y_ws, W2, b2, s_ws, Vbf, outp);
}

// Round 3
// 11799.749 us; speedup vs baseline: 1.0460x; 1.0460x over previous
//
#include <hip/hip_runtime.h>
#include <hip/hip_bf16.h>
#include <hip/hip_fp16.h>

#define NSWEEP 12

static constexpr int NAP = 128;
static constexpr int NU  = 128;
static constexpr int F_  = 10;
static constexpr int BF  = 640;   // B*F
static constexpr int HID = 100;

// ---------------- Kernel 1: one-sided (Hestenes) Jacobi, register-resident --
// 64 groups x 8 lanes. Group g holds two columns (T,B) of G and V in regs.
// Brent-Luk tournament: T-chain shifts +1 group, B-chain shifts -1 group,
// realized by +-8-lane shuffles; wave-boundary columns go through LDS
// (double-buffered -> 1 barrier per round).
__global__ __launch_bounds__(512, 4)
void eig_kernel(const float* __restrict__ Ain,
                float* __restrict__ e_out,          // [BF][128]
                float* __restrict__ s_out,          // [BF][128]
                __half* __restrict__ V_out)         // [BF][128][128] row-major
{
    __shared__ float xT[2][8][2][128];   // [buf][src wave][G/V][elem]
    __shared__ float xB[2][8][2][128];
    __shared__ float key[128];
    __shared__ float csum[128];
    __shared__ int   idxs[128];
    __shared__ int   rankv[128];

    const int tid = threadIdx.x;
    const int g   = tid >> 3;        // group 0..63
    const int s   = tid & 7;         // sub-lane in group
    const int gl  = g & 7;           // group index within wave
    const int w   = tid >> 6;        // wave 0..7
    const int m   = blockIdx.x;
    const int bb  = m / F_;
    const int ff  = m % F_;
    const int k16 = s * 16;

    float GT[16], GB[16], VT[16], VB[16];

    // init: G columns = A[:,u] (u = g for T, 64+g for B), V = I
    {
        const float* Ab = Ain + (size_t)bb * NAP * NU * F_ + ff;
        #pragma unroll
        for (int i = 0; i < 16; ++i) {
            const int k = k16 + i;
            GT[i] = Ab[(size_t)(k * NU + g) * F_];
            GB[i] = Ab[(size_t)(k * NU + 64 + g) * F_];
            VT[i] = (k == g)      ? 1.f : 0.f;
            VB[i] = (k == 64 + g) ? 1.f : 0.f;
        }
    }

    const bool isg0  = (g == 0);
    const bool isg63 = (g == 63);
    const bool sndT  = (gl == 7);              // writes outgoing T to LDS
    const bool sndB  = (gl == 0);              // writes outgoing B to LDS
    const bool bndT  = (gl == 0) && (w > 0);   // receives T via LDS
    const bool bndB  = (gl == 7) && !isg63;    // receives B via LDS

    for (int rnd = 0; rnd < NSWEEP * 127; ++rnd) {
        // ---- dots: pp = gT.gT, qq = gB.gB, pq = gT.gB ----
        float pp = 0.f, qq = 0.f, pq = 0.f;
        #pragma unroll
        for (int i = 0; i < 16; ++i) {
            pp = fmaf(GT[i], GT[i], pp);
            qq = fmaf(GB[i], GB[i], qq);
            pq = fmaf(GT[i], GB[i], pq);
        }
        #pragma unroll
        for (int d = 1; d < 8; d <<= 1) {
            pp += __shfl_xor(pp, d);
            qq += __shfl_xor(qq, d);
            pq += __shfl_xor(pq, d);
        }
        // ---- rotation zeroing the 2x2 Gram off-diagonal ----
        float c = 1.f, sn = 0.f;
        if (pq * pq > 1e-24f * pp * qq) {
            const float tau = (qq - pp) / (2.f * pq);
            float t = 1.f / (fabsf(tau) + sqrtf(1.f + tau * tau));
            if (tau < 0.f) t = -t;
            c  = 1.f / sqrtf(1.f + t * t);
            sn = t * c;
        }
        #pragma unroll
        for (int i = 0; i < 16; ++i) {
            const float gp = GT[i], gq = GB[i];
            GT[i] = c * gp - sn * gq;
            GB[i] = sn * gp + c * gq;
            const float vp = VT[i], vq = VB[i];
            VT[i] = c * vp - sn * vq;
            VB[i] = sn * vp + c * vq;
        }

        // ---- exchange (Brent-Luk) ----
        const int bp = rnd & 1;
        if (sndT) {  // gl==7: outgoing T = GT (g is never 0 here)
            float4* dG = (float4*)&xT[bp][w][0][k16];
            float4* dV = (float4*)&xT[bp][w][1][k16];
            dG[0] = make_float4(GT[0], GT[1], GT[2], GT[3]);
            dG[1] = make_float4(GT[4], GT[5], GT[6], GT[7]);
            dG[2] = make_float4(GT[8], GT[9], GT[10], GT[11]);
            dG[3] = make_float4(GT[12], GT[13], GT[14], GT[15]);
            dV[0] = make_float4(VT[0], VT[1], VT[2], VT[3]);
            dV[1] = make_float4(VT[4], VT[5], VT[6], VT[7]);
            dV[2] = make_float4(VT[8], VT[9], VT[10], VT[11]);
            dV[3] = make_float4(VT[12], VT[13], VT[14], VT[15]);
        }
        if (sndB) {  // gl==0: outgoing B = GB
            float4* dG = (float4*)&xB[bp][w][0][k16];
            float4* dV = (float4*)&xB[bp][w][1][k16];
            dG[0] = make_float4(GB[0], GB[1], GB[2], GB[3]);
            dG[1] = make_float4(GB[4], GB[5], GB[6], GB[7]);
            dG[2] = make_float4(GB[8], GB[9], GB[10], GB[11]);
            dG[3] = make_float4(GB[12], GB[13], GB[14], GB[15]);
            dV[0] = make_float4(VB[0], VB[1], VB[2], VB[3]);
            dV[1] = make_float4(VB[4], VB[5], VB[6], VB[7]);
            dV[2] = make_float4(VB[8], VB[9], VB[10], VB[11]);
            dV[3] = make_float4(VB[12], VB[13], VB[14], VB[15]);
        }
        __syncthreads();

        // intra-wave shifts: T-chain from lane-8, B-chain from lane+8
        #pragma unroll
        for (int i = 0; i < 16; ++i) {
            const float oT = GT[i], oB = GB[i];
            const float vT = VT[i], vB = VB[i];
            const float outTG = isg0 ? oB : oT;   // B[0] enters T-chain at T[1]
            const float outTV = isg0 ? vB : vT;
            const float sTg = __shfl_up(outTG, 8);
            const float sTv = __shfl_up(outTV, 8);
            const float sBg = __shfl_down(oB, 8);
            const float sBv = __shfl_down(vB, 8);
            GT[i] = isg0  ? oT : sTg;             // T[0] fixed
            VT[i] = isg0  ? vT : sTv;
            GB[i] = isg63 ? oT : sBg;             // T[63] enters B-chain at B[63]
            VB[i] = isg63 ? vT : sBv;
        }
        if (bndT) {  // gl==0, w>0: T from previous wave's gl==7
            const float4* rG = (const float4*)&xT[bp][w - 1][0][k16];
            const float4* rV = (const float4*)&xT[bp][w - 1][1][k16];
            float4 a0 = rG[0], a1 = rG[1], a2 = rG[2], a3 = rG[3];
            GT[0]=a0.x; GT[1]=a0.y; GT[2]=a0.z; GT[3]=a0.w;
            GT[4]=a1.x; GT[5]=a1.y; GT[6]=a1.z; GT[7]=a1.w;
            GT[8]=a2.x; GT[9]=a2.y; GT[10]=a2.z; GT[11]=a2.w;
            GT[12]=a3.x; GT[13]=a3.y; GT[14]=a3.z; GT[15]=a3.w;
            float4 b0 = rV[0], b1 = rV[1], b2 = rV[2], b3 = rV[3];
            VT[0]=b0.x; VT[1]=b0.y; VT[2]=b0.z; VT[3]=b0.w;
            VT[4]=b1.x; VT[5]=b1.y; VT[6]=b1.z; VT[7]=b1.w;
            VT[8]=b2.x; VT[9]=b2.y; VT[10]=b2.z; VT[11]=b2.w;
            VT[12]=b3.x; VT[13]=b3.y; VT[14]=b3.z; VT[15]=b3.w;
        }
        if (bndB) {  // gl==7, g!=63: B from next wave's gl==0
            const float4* rG = (const float4*)&xB[bp][w + 1][0][k16];
            const float4* rV = (const float4*)&xB[bp][w + 1][1][k16];
            float4 a0 = rG[0], a1 = rG[1], a2 = rG[2], a3 = rG[3];
            GB[0]=a0.x; GB[1]=a0.y; GB[2]=a0.z; GB[3]=a0.w;
            GB[4]=a1.x; GB[5]=a1.y; GB[6]=a1.z; GB[7]=a1.w;
            GB[8]=a2.x; GB[9]=a2.y; GB[10]=a2.z; GB[11]=a2.w;
            GB[12]=a3.x; GB[13]=a3.y; GB[14]=a3.z; GB[15]=a3.w;
            float4 b0 = rV[0], b1 = rV[1], b2 = rV[2], b3 = rV[3];
            VB[0]=b0.x; VB[1]=b0.y; VB[2]=b0.z; VB[3]=b0.w;
            VB[4]=b1.x; VB[5]=b1.y; VB[6]=b1.z; VB[7]=b1.w;
            VB[8]=b2.x; VB[9]=b2.y; VB[10]=b2.z; VB[11]=b2.w;
            VB[12]=b3.x; VB[13]=b3.y; VB[14]=b3.z; VB[15]=b3.w;
        }
    }

    // ---- epilogue: eigenvalues = |g_j|^2, colsums of V, sort, emit ----
    {
        float aT = 0.f, aB = 0.f, cT = 0.f, cB = 0.f;
        #pragma unroll
        for (int i = 0; i < 16; ++i) {
            aT = fmaf(GT[i], GT[i], aT);
            aB = fmaf(GB[i], GB[i], aB);
            cT += VT[i];
            cB += VB[i];
        }
        #pragma unroll
        for (int d = 1; d < 8; d <<= 1) {
            aT += __shfl_xor(aT, d);
            aB += __shfl_xor(aB, d);
            cT += __shfl_xor(cT, d);
            cB += __shfl_xor(cB, d);
        }
        if (s == 0) {
            key[g] = aT;  key[64 + g] = aB;
            csum[g] = cT; csum[64 + g] = cB;
        }
    }
    __syncthreads();
    if (tid < 128) idxs[tid] = tid;
    __syncthreads();
    for (int kk = 2; kk <= 128; kk <<= 1) {
        for (int jj = kk >> 1; jj > 0; jj >>= 1) {
            if (tid < 128) {
                const int i = tid, l = i ^ jj;
                if (l > i) {
                    const bool up = ((i & kk) == 0);
                    const float ki = key[i], kl = key[l];
                    if ((ki > kl) == up) {
                        const int ii = idxs[i], il = idxs[l];
                        key[i] = kl; key[l] = ki;
                        idxs[i] = il; idxs[l] = ii;
                    }
                }
            }
            __syncthreads();
        }
    }
    if (tid < 128) rankv[idxs[tid]] = tid;
    __syncthreads();
    if (tid < 128) {
        e_out[(size_t)m * 128 + tid] = key[tid];
        s_out[(size_t)m * 128 + tid] = csum[idxs[tid]] * (1.f / 128.f);
    }
    {
        const int jT = rankv[g], jB = rankv[64 + g];
        __half* Vb = V_out + (size_t)m * 16384;
        #pragma unroll
        for (int i = 0; i < 16; ++i) {
            const int k = k16 + i;
            Vb[k * 128 + jT] = __float2half(VT[i]);
            Vb[k * 128 + jB] = __float2half(VB[i]);
        }
    }
}

// ---------------- Kernel 2: MLP on eigenvalues (128 -> 100 -> 100) --------
__global__ __launch_bounds__(128)
void mlp_kernel(const float* __restrict__ e_in,   // [BF][128]
                const float* __restrict__ W0,     // [128][100]
                const float* __restrict__ b0,
                const float* __restrict__ W1,     // [100][100]
                const float* __restrict__ b1,
                float* __restrict__ y_out)        // [BF][100]
{
    __shared__ float ein[128];
    __shared__ float h0[HID];
    const int m = blockIdx.x;
    const int tid = threadIdx.x;
    ein[tid] = e_in[(size_t)m * 128 + tid];
    __syncthreads();
    if (tid < HID) {
        float a = b0[tid];
        for (int i = 0; i < 128; ++i) a += ein[i] * W0[i * HID + tid];
        h0[tid] = fmaxf(a, 0.f);
    }
    __syncthreads();
    if (tid < HID) {
        float a = b1[tid];
        for (int h = 0; h < HID; ++h) a += h0[h] * W1[h * HID + tid];
        y_out[(size_t)m * HID + tid] = fmaxf(a, 0.f);
    }
}

// ---------------- Kernel 3: D = Ysub@W2blk + b2; Out = (D*s)@V^T; exp -----
__global__ __launch_bounds__(256)
void final_kernel(const float* __restrict__ y,     // [BF][100]
                  const float* __restrict__ W2,    // [100][16384]
                  const float* __restrict__ b2,    // [16384]
                  const float* __restrict__ s_in,  // [BF][128]
                  const __half* __restrict__ V_in, // [BF][128][128]
                  float* __restrict__ outp)        // [BF][128][128]
{
    extern __shared__ float lds[];
    float* Vs  = lds;            // [128][129] (filled in phase 2)
    float* Wm  = lds + 16512;    // [128][129]
    float* Ys  = lds;            // [128][101] staging (overlaps Vs)
    float* W2s = lds + 12928;    // [100][128] staging (overlaps Vs/Wm)

    const int m    = blockIdx.x;
    const int m_hi = m >> 7, m_lo = m & 127;
    const int tid  = threadIdx.x;
    const int tx   = tid & 15, ty = tid >> 4;

    for (int u = tid; u < 128 * 100; u += 256) {
        const int t = u / 100, h = u - t * 100;
        Ys[t * 101 + h] = y[(size_t)(5 * t + m_hi) * 100 + h];
    }
    for (int u = tid; u < 100 * 128; u += 256) {
        const int h = u >> 7, c = u & 127;
        W2s[h * 128 + c] = W2[(size_t)h * 16384 + (size_t)m_lo * 128 + c];
    }
    __syncthreads();

    float acc[8][8];
    #pragma unroll
    for (int a = 0; a < 8; ++a)
        #pragma unroll
        for (int c = 0; c < 8; ++c) acc[a][c] = 0.f;
    for (int h = 0; h < 100; ++h) {
        float yv[8], wv[8];
        #pragma unroll
        for (int a = 0; a < 8; ++a) yv[a] = Ys[(ty + 16 * a) * 101 + h];
        #pragma unroll
        for (int c = 0; c < 8; ++c) wv[c] = W2s[h * 128 + tx + 16 * c];
        #pragma unroll
        for (int a = 0; a < 8; ++a)
            #pragma unroll
            for (int c = 0; c < 8; ++c) acc[a][c] += yv[a] * wv[c];
    }
    {
        float b2v[8], sv[8];
        #pragma unroll
        for (int c = 0; c < 8; ++c) {
            b2v[c] = b2[m_lo * 128 + tx + 16 * c];
            sv[c]  = s_in[(size_t)m * 128 + tx + 16 * c];
        }
        #pragma unroll
        for (int a = 0; a < 8; ++a)
            #pragma unroll
            for (int c = 0; c < 8; ++c)
                acc[a][c] = (acc[a][c] + b2v[c]) * sv[c];
    }
    __syncthreads();

    #pragma unroll
    for (int a = 0; a < 8; ++a)
        #pragma unroll
        for (int c = 0; c < 8; ++c)
            Wm[(ty + 16 * a) * 129 + tx + 16 * c] = acc[a][c];
    for (int u = tid; u < 16384; u += 256) {
        const int i = u >> 7, j = u & 127;
        Vs[i * 129 + j] = __half2float(V_in[(size_t)m * 16384 + u]);
    }
    __syncthreads();

    float o[8][8];
    #pragma unroll
    for (int a = 0; a < 8; ++a)
        #pragma unroll
        for (int c = 0; c < 8; ++c) o[a][c] = 0.f;
    for (int j = 0; j < 128; ++j) {
        float wv[8], vv[8];
        #pragma unroll
        for (int a = 0; a < 8; ++a) wv[a] = Wm[(ty + 16 * a) * 129 + j];
        #pragma unroll
        for (int c = 0; c < 8; ++c) vv[c] = Vs[(tx + 16 * c) * 129 + j];
        #pragma unroll
        for (int a = 0; a < 8; ++a)
            #pragma unroll
            for (int c = 0; c < 8; ++c) o[a][c] += wv[a] * vv[c];
    }
    #pragma unroll
    for (int a = 0; a < 8; ++a) {
        const int t = ty + 16 * a;
        const size_t rowbase = (size_t)(5 * t + m_hi) * 16384 + (size_t)m_lo * 128;
        #pragma unroll
        for (int c = 0; c < 8; ++c)
            outp[rowbase + tx + 16 * c] = expf(o[a][c]);
    }
}

// ---------------------------------------------------------------------------
extern "C" void kernel_launch(void* const* d_in, const int* in_sizes, int n_in,
                              void* d_out, int out_size, void* d_ws, size_t ws_size,
                              hipStream_t stream)
{
    const float* Ain = (const float*)d_in[0];
    const float* W0  = (const float*)d_in[1];
    const float* b0  = (const float*)d_in[2];
    const float* W1  = (const float*)d_in[3];
    const float* b1  = (const float*)d_in[4];
    const float* W2  = (const float*)d_in[5];
    const float* b2  = (const float*)d_in[6];
    float* outp = (float*)d_out;

    char* ws = (char*)d_ws;
    __half* Vh  = (__half*)ws;                               // 640*16384*2 = 20971520 B
    float* e_ws = (float*)(ws + 20971520);                   // 640*128*4
    float* s_ws = (float*)(ws + 20971520 + 327680);          // 640*128*4
    float* y_ws = (float*)(ws + 20971520 + 655360);          // 640*100*4

    const size_t lds_bytes = (size_t)(2 * 128 * 129) * sizeof(float); // 132096

    eig_kernel<<<dim3(BF), dim3(512), 0, stream>>>(Ain, e_ws, s_ws, Vh);
    mlp_kernel<<<dim3(BF), dim3(128), 0, stream>>>(e_ws, W0, b0, W1, b1, y_ws);
    final_kernel<<<dim3(BF), dim3(256), lds_bytes, stream>>>(y_ws, W2, b2, s_ws, Vh, outp);
}

// Round 4
// 6094.949 us; speedup vs baseline: 2.0250x; 1.9360x over previous
//
#include <hip/hip_runtime.h>
#include <hip/hip_fp16.h>

#define NSWEEP 12

static constexpr int F_  = 10;
static constexpr int BF  = 640;   // B*F
static constexpr int HID = 100;
static constexpr float MU = 512.0f;   // ~lambda_max of Wishart(128,128)

// 8-lane DPP butterfly add: xor1 (quad_perm [1,0,3,2]), xor2 (quad_perm
// [2,3,0,1]), xor7 (row_half_mirror) -- groups are 8-lane aligned, so each
// group lies in one half-row of 16. All VALU, no ds pipe.
template<int CTRL>
__device__ __forceinline__ float dpp_add(float x) {
    int t = __builtin_amdgcn_update_dpp(0, __float_as_int(x), CTRL, 0xF, 0xF, false);
    return x + __int_as_float(t);
}
__device__ __forceinline__ float reduce8(float x) {
    x = dpp_add<0xB1>(x);
    x = dpp_add<0x4E>(x);
    x = dpp_add<0x141>(x);
    return x;
}

// ---------------- Kernel 1: Gram(+shift) + one-sided Jacobi, no V accum ----
// 64 groups x 8 lanes. Group g holds two columns (T,B) of G = (L+MU*I)*Racc
// in registers. Brent-Luk tournament via +-8-lane shuffles; wave-boundary
// columns via double-buffered LDS (1 barrier/round). At convergence
// ||g_j|| = lambda_j + MU and v_j = g_j / ||g_j||.
__global__ __launch_bounds__(512, 4)
void eig_kernel(const float* __restrict__ Ain,
                float* __restrict__ e_out,          // [BF][128]
                float* __restrict__ s_out,          // [BF][128]
                __half* __restrict__ V_out)         // [BF][128][128] row-major
{
    __shared__ float SH[128 * 128];    // A staging; first 4K floats reused as xT/xB
    __shared__ float key[128];
    __shared__ float csum[128];
    __shared__ int   idxs[128];
    __shared__ int   rankv[128];

    float* xT = SH;          // [2][8][128]
    float* xB = SH + 2048;   // [2][8][128]

    const int tid = threadIdx.x;
    const int g   = tid >> 3;        // group 0..63
    const int s   = tid & 7;         // sub-lane in group
    const int gl  = g & 7;           // group index within wave
    const int w   = tid >> 6;        // wave 0..7
    const int m   = blockIdx.x;
    const int bb  = m / F_;
    const int ff  = m % F_;
    const int k16 = s * 16;

    // ---- stage A[k][col] into SH ----
    {
        const float* Ab = Ain + (size_t)bb * 128 * 128 * F_ + ff;
        for (int t = tid; t < 128 * 128; t += 512)
            SH[t] = Ab[(size_t)t * F_];
    }
    __syncthreads();

    // ---- G columns: GT = (L+MU*I)[:,g] rows k16..k16+15, GB = col 64+g ----
    float GT[16], GB[16];
    #pragma unroll
    for (int i = 0; i < 16; ++i) {
        GT[i] = (k16 + i == g)      ? MU : 0.f;
        GB[i] = (k16 + i == 64 + g) ? MU : 0.f;
    }
    for (int k = 0; k < 128; ++k) {
        const float4 a0 = *(const float4*)&SH[k * 128 + k16];
        const float4 a1 = *(const float4*)&SH[k * 128 + k16 + 4];
        const float4 a2 = *(const float4*)&SH[k * 128 + k16 + 8];
        const float4 a3 = *(const float4*)&SH[k * 128 + k16 + 12];
        const float atg = SH[k * 128 + g];
        const float abg = SH[k * 128 + 64 + g];
        float ar[16] = {a0.x,a0.y,a0.z,a0.w, a1.x,a1.y,a1.z,a1.w,
                        a2.x,a2.y,a2.z,a2.w, a3.x,a3.y,a3.z,a3.w};
        #pragma unroll
        for (int i = 0; i < 16; ++i) {
            GT[i] = fmaf(ar[i], atg, GT[i]);
            GB[i] = fmaf(ar[i], abg, GB[i]);
        }
    }
    __syncthreads();   // SH (A) dead; xT/xB region live from here

    const bool isg0  = (g == 0);
    const bool isg63 = (g == 63);
    const bool sndT  = (gl == 7);              // writes outgoing T to LDS
    const bool sndB  = (gl == 0);              // writes outgoing B to LDS
    const bool bndT  = (gl == 0) && (w > 0);   // receives T via LDS
    const bool bndB  = (gl == 7) && !isg63;    // receives B via LDS

    for (int rnd = 0; rnd < NSWEEP * 127; ++rnd) {
        // ---- 2x2 Gram of the pair ----
        float pp = 0.f, qq = 0.f, pq = 0.f;
        #pragma unroll
        for (int i = 0; i < 16; ++i) {
            pp = fmaf(GT[i], GT[i], pp);
            qq = fmaf(GB[i], GB[i], qq);
            pq = fmaf(GT[i], GB[i], pq);
        }
        pp = reduce8(pp); qq = reduce8(qq); pq = reduce8(pq);

        float c = 1.f, sn = 0.f;
        if (pq * pq > 1e-24f * pp * qq) {
            const float tau = (qq - pp) / (2.f * pq);
            float t = 1.f / (fabsf(tau) + sqrtf(1.f + tau * tau));
            if (tau < 0.f) t = -t;
            c  = 1.f / sqrtf(1.f + t * t);
            sn = t * c;
        }
        #pragma unroll
        for (int i = 0; i < 16; ++i) {
            const float gp = GT[i], gq = GB[i];
            GT[i] = c * gp - sn * gq;
            GB[i] = sn * gp + c * gq;
        }

        // ---- Brent-Luk exchange ----
        const int bp = rnd & 1;
        if (sndT) {
            float4* d = (float4*)&xT[(bp * 8 + w) * 128 + k16];
            d[0] = make_float4(GT[0], GT[1], GT[2], GT[3]);
            d[1] = make_float4(GT[4], GT[5], GT[6], GT[7]);
            d[2] = make_float4(GT[8], GT[9], GT[10], GT[11]);
            d[3] = make_float4(GT[12], GT[13], GT[14], GT[15]);
        }
        if (sndB) {
            float4* d = (float4*)&xB[(bp * 8 + w) * 128 + k16];
            d[0] = make_float4(GB[0], GB[1], GB[2], GB[3]);
            d[1] = make_float4(GB[4], GB[5], GB[6], GB[7]);
            d[2] = make_float4(GB[8], GB[9], GB[10], GB[11]);
            d[3] = make_float4(GB[12], GB[13], GB[14], GB[15]);
        }
        __syncthreads();

        #pragma unroll
        for (int i = 0; i < 16; ++i) {
            const float oT = GT[i], oB = GB[i];
            const float outT = isg0 ? oB : oT;    // B[0] enters T-chain at T[1]
            const float sT = __shfl_up(outT, 8);
            const float sB = __shfl_down(oB, 8);
            GT[i] = isg0  ? oT : sT;              // T[0] fixed
            GB[i] = isg63 ? oT : sB;              // T[63] enters B-chain
        }
        if (bndT) {
            const float4* r = (const float4*)&xT[(bp * 8 + w - 1) * 128 + k16];
            float4 a0 = r[0], a1 = r[1], a2 = r[2], a3 = r[3];
            GT[0]=a0.x; GT[1]=a0.y; GT[2]=a0.z; GT[3]=a0.w;
            GT[4]=a1.x; GT[5]=a1.y; GT[6]=a1.z; GT[7]=a1.w;
            GT[8]=a2.x; GT[9]=a2.y; GT[10]=a2.z; GT[11]=a2.w;
            GT[12]=a3.x; GT[13]=a3.y; GT[14]=a3.z; GT[15]=a3.w;
        }
        if (bndB) {
            const float4* r = (const float4*)&xB[(bp * 8 + w + 1) * 128 + k16];
            float4 a0 = r[0], a1 = r[1], a2 = r[2], a3 = r[3];
            GB[0]=a0.x; GB[1]=a0.y; GB[2]=a0.z; GB[3]=a0.w;
            GB[4]=a1.x; GB[5]=a1.y; GB[6]=a1.z; GB[7]=a1.w;
            GB[8]=a2.x; GB[9]=a2.y; GB[10]=a2.z; GB[11]=a2.w;
            GB[12]=a3.x; GB[13]=a3.y; GB[14]=a3.z; GB[15]=a3.w;
        }
    }

    // ---- epilogue: norms -> eigenvalues, colsums -> s, normalized G -> V ----
    float aT = 0.f, aB = 0.f, cT = 0.f, cB = 0.f;
    #pragma unroll
    for (int i = 0; i < 16; ++i) {
        aT = fmaf(GT[i], GT[i], aT);
        aB = fmaf(GB[i], GB[i], aB);
        cT += GT[i];
        cB += GB[i];
    }
    aT = reduce8(aT); aB = reduce8(aB);
    cT = reduce8(cT); cB = reduce8(cB);
    const float invT = 1.f / sqrtf(aT);
    const float invB = 1.f / sqrtf(aB);
    if (s == 0) {
        key[g] = aT;  key[64 + g] = aB;
        csum[g]      = cT * invT * (1.f / 128.f);
        csum[64 + g] = cB * invB * (1.f / 128.f);
    }
    __syncthreads();
    if (tid < 128) idxs[tid] = tid;
    __syncthreads();
    for (int kk = 2; kk <= 128; kk <<= 1) {
        for (int jj = kk >> 1; jj > 0; jj >>= 1) {
            if (tid < 128) {
                const int i = tid, l = i ^ jj;
                if (l > i) {
                    const bool up = ((i & kk) == 0);
                    const float ki = key[i], kl = key[l];
                    if ((ki > kl) == up) {
                        const int ii = idxs[i], il = idxs[l];
                        key[i] = kl; key[l] = ki;
                        idxs[i] = il; idxs[l] = ii;
                    }
                }
            }
            __syncthreads();
        }
    }
    if (tid < 128) rankv[idxs[tid]] = tid;
    __syncthreads();
    if (tid < 128) {
        e_out[(size_t)m * 128 + tid] = sqrtf(key[tid]) - MU;
        s_out[(size_t)m * 128 + tid] = csum[idxs[tid]];
    }
    {
        const int jT = rankv[g], jB = rankv[64 + g];
        __half* Vb = V_out + (size_t)m * 16384;
        #pragma unroll
        for (int i = 0; i < 16; ++i) {
            const int k = k16 + i;
            Vb[k * 128 + jT] = __float2half(GT[i] * invT);
            Vb[k * 128 + jB] = __float2half(GB[i] * invB);
        }
    }
}

// ---------------- Kernel 2: MLP on eigenvalues (128 -> 100 -> 100) --------
__global__ __launch_bounds__(128)
void mlp_kernel(const float* __restrict__ e_in,   // [BF][128]
                const float* __restrict__ W0,     // [128][100]
                const float* __restrict__ b0,
                const float* __restrict__ W1,     // [100][100]
                const float* __restrict__ b1,
                float* __restrict__ y_out)        // [BF][100]
{
    __shared__ float ein[128];
    __shared__ float h0[HID];
    const int m = blockIdx.x;
    const int tid = threadIdx.x;
    ein[tid] = e_in[(size_t)m * 128 + tid];
    __syncthreads();
    if (tid < HID) {
        float a = b0[tid];
        for (int i = 0; i < 128; ++i) a += ein[i] * W0[i * HID + tid];
        h0[tid] = fmaxf(a, 0.f);
    }
    __syncthreads();
    if (tid < HID) {
        float a = b1[tid];
        for (int h = 0; h < HID; ++h) a += h0[h] * W1[h * HID + tid];
        y_out[(size_t)m * HID + tid] = fmaxf(a, 0.f);
    }
}

// ---------------- Kernel 3: D = Ysub@W2blk + b2; Out = (D*s)@V^T; exp -----
__global__ __launch_bounds__(256)
void final_kernel(const float* __restrict__ y,     // [BF][100]
                  const float* __restrict__ W2,    // [100][16384]
                  const float* __restrict__ b2,    // [16384]
                  const float* __restrict__ s_in,  // [BF][128]
                  const __half* __restrict__ V_in, // [BF][128][128]
                  float* __restrict__ outp)        // [BF][128][128]
{
    extern __shared__ float lds[];
    float* Vs  = lds;            // [128][129] (filled in phase 2)
    float* Wm  = lds + 16512;    // [128][129]
    float* Ys  = lds;            // [128][101] staging (overlaps Vs)
    float* W2s = lds + 12928;    // [100][128] staging (overlaps Vs/Wm)

    const int m    = blockIdx.x;
    const int m_hi = m >> 7, m_lo = m & 127;
    const int tid  = threadIdx.x;
    const int tx   = tid & 15, ty = tid >> 4;

    for (int u = tid; u < 128 * 100; u += 256) {
        const int t = u / 100, h = u - t * 100;
        Ys[t * 101 + h] = y[(size_t)(5 * t + m_hi) * 100 + h];
    }
    for (int u = tid; u < 100 * 128; u += 256) {
        const int h = u >> 7, c = u & 127;
        W2s[h * 128 + c] = W2[(size_t)h * 16384 + (size_t)m_lo * 128 + c];
    }
    __syncthreads();

    float acc[8][8];
    #pragma unroll
    for (int a = 0; a < 8; ++a)
        #pragma unroll
        for (int c = 0; c < 8; ++c) acc[a][c] = 0.f;
    for (int h = 0; h < 100; ++h) {
        float yv[8], wv[8];
        #pragma unroll
        for (int a = 0; a < 8; ++a) yv[a] = Ys[(ty + 16 * a) * 101 + h];
        #pragma unroll
        for (int c = 0; c < 8; ++c) wv[c] = W2s[h * 128 + tx + 16 * c];
        #pragma unroll
        for (int a = 0; a < 8; ++a)
            #pragma unroll
            for (int c = 0; c < 8; ++c) acc[a][c] += yv[a] * wv[c];
    }
    {
        float b2v[8], sv[8];
        #pragma unroll
        for (int c = 0; c < 8; ++c) {
            b2v[c] = b2[m_lo * 128 + tx + 16 * c];
            sv[c]  = s_in[(size_t)m * 128 + tx + 16 * c];
        }
        #pragma unroll
        for (int a = 0; a < 8; ++a)
            #pragma unroll
            for (int c = 0; c < 8; ++c)
                acc[a][c] = (acc[a][c] + b2v[c]) * sv[c];
    }
    __syncthreads();

    #pragma unroll
    for (int a = 0; a < 8; ++a)
        #pragma unroll
        for (int c = 0; c < 8; ++c)
            Wm[(ty + 16 * a) * 129 + tx + 16 * c] = acc[a][c];
    for (int u = tid; u < 16384; u += 256) {
        const int i = u >> 7, j = u & 127;
        Vs[i * 129 + j] = __half2float(V_in[(size_t)m * 16384 + u]);
    }
    __syncthreads();

    float o[8][8];
    #pragma unroll
    for (int a = 0; a < 8; ++a)
        #pragma unroll
        for (int c = 0; c < 8; ++c) o[a][c] = 0.f;
    for (int j = 0; j < 128; ++j) {
        float wv[8], vv[8];
        #pragma unroll
        for (int a = 0; a < 8; ++a) wv[a] = Wm[(ty + 16 * a) * 129 + j];
        #pragma unroll
        for (int c = 0; c < 8; ++c) vv[c] = Vs[(tx + 16 * c) * 129 + j];
        #pragma unroll
        for (int a = 0; a < 8; ++a)
            #pragma unroll
            for (int c = 0; c < 8; ++c) o[a][c] += wv[a] * vv[c];
    }
    #pragma unroll
    for (int a = 0; a < 8; ++a) {
        const int t = ty + 16 * a;
        const size_t rowbase = (size_t)(5 * t + m_hi) * 16384 + (size_t)m_lo * 128;
        #pragma unroll
        for (int c = 0; c < 8; ++c)
            outp[rowbase + tx + 16 * c] = expf(o[a][c]);
    }
}

// ---------------------------------------------------------------------------
extern "C" void kernel_launch(void* const* d_in, const int* in_sizes, int n_in,
                              void* d_out, int out_size, void* d_ws, size_t ws_size,
                              hipStream_t stream)
{
    const float* Ain = (const float*)d_in[0];
    const float* W0  = (const float*)d_in[1];
    const float* b0  = (const float*)d_in[2];
    const float* W1  = (const float*)d_in[3];
    const float* b1  = (const float*)d_in[4];
    const float* W2  = (const float*)d_in[5];
    const float* b2  = (const float*)d_in[6];
    float* outp = (float*)d_out;

    char* ws = (char*)d_ws;
    __half* Vh  = (__half*)ws;                               // 640*16384*2 = 20971520 B
    float* e_ws = (float*)(ws + 20971520);                   // 640*128*4
    float* s_ws = (float*)(ws + 20971520 + 327680);          // 640*128*4
    float* y_ws = (float*)(ws + 20971520 + 655360);          // 640*100*4

    const size_t lds_bytes = (size_t)(2 * 128 * 129) * sizeof(float); // 132096

    eig_kernel<<<dim3(BF), dim3(512), 0, stream>>>(Ain, e_ws, s_ws, Vh);
    mlp_kernel<<<dim3(BF), dim3(128), 0, stream>>>(e_ws, W0, b0, W1, b1, y_ws);
    final_kernel<<<dim3(BF), dim3(256), lds_bytes, stream>>>(y_ws, W2, b2, s_ws, Vh, outp);
}

// Round 5
// 5288.548 us; speedup vs baseline: 2.3338x; 1.1525x over previous
//
#include <hip/hip_runtime.h>
#include <hip/hip_fp16.h>

#define NSWEEP 12

static constexpr int F_  = 10;
static constexpr int BF  = 640;   // B*F
static constexpr int HID = 100;
static constexpr float MU = 512.0f;   // ~lambda_max of Wishart(128,128)

// quad (4-lane) butterfly all-reduce add via DPP: xor1, xor2. Bitwise
// identical result on all 4 lanes (fp add of same operands, commutative).
template<int CTRL>
__device__ __forceinline__ float dpp_add(float x) {
    int t = __builtin_amdgcn_update_dpp(0, __float_as_int(x), CTRL, 0xF, 0xF, false);
    return x + __int_as_float(t);
}
__device__ __forceinline__ float quad_reduce(float x) {
    x = dpp_add<0xB1>(x);   // xor 1 (quad_perm [1,0,3,2])
    x = dpp_add<0x4E>(x);   // xor 2 (quad_perm [2,3,0,1])
    return x;
}

// One Jacobi rotation of this lane's column against partner lane `plane`.
// isp: this column acts as p (lower index) of the pair. Updates G and the
// maintained squared norm pp. Both sides compute bitwise-identical (c,s).
__device__ __forceinline__ void jrot(float (&G)[32], float& pp,
                                     const int plane, const bool isp) {
    float part[32];
    #pragma unroll
    for (int i = 0; i < 32; ++i) part[i] = __shfl(G[i], plane);
    float pq = 0.f;
    #pragma unroll
    for (int i = 0; i < 32; ++i) pq = fmaf(G[i], part[i], pq);
    pq = quad_reduce(pq);
    const float qn  = __shfl(pp, plane);
    const float app = isp ? pp : qn;
    const float aqq = isp ? qn : pp;
    float c = 1.f, sn = 0.f, t = 0.f;
    if (pq * pq > 1e-28f * app * aqq) {
        const float tau = (aqq - app) / (2.f * pq);
        float t3 = 1.f / (fabsf(tau) + sqrtf(1.f + tau * tau));
        if (tau < 0.f) t3 = -t3;
        t  = t3;
        c  = 1.f / sqrtf(1.f + t3 * t3);
        sn = t3 * c;
    }
    const float sgn = isp ? -sn : sn;
    #pragma unroll
    for (int i = 0; i < 32; ++i) G[i] = fmaf(sgn, part[i], c * G[i]);
    pp = fmaf(isp ? -t : t, pq, pp);
}

__device__ __forceinline__ float normsq(const float (&G)[32]) {
    float a = 0.f;
    #pragma unroll
    for (int i = 0; i < 32; ++i) a = fmaf(G[i], G[i], a);
    return quad_reduce(a);
}

// ---------------- Kernel 1: Gram(+shift) + block-cyclic one-sided Jacobi ---
// 8 waves x 16 columns (4 lanes/col, 32 elem/lane, fixed residency).
// Sweep = 15-round intra-wave XOR tournament (no barriers) + 15 block-rounds
// of 8 barrier-free cross rounds, with half-block movement via LDS between
// block-rounds (2 barriers each). lambda_j = ||g_j|| - MU, v_j = g_j/||g_j||.
__global__ __launch_bounds__(512, 4)
void eig_kernel(const float* __restrict__ Ain,
                float* __restrict__ e_out,          // [BF][128]
                float* __restrict__ s_out,          // [BF][128]
                __half* __restrict__ V_out)         // [BF][128 cols][128 k] (transposed)
{
    __shared__ float SH[16384];   // XT[8][8][128] | XB[8][8][128]; Gram chunk overlaps
    __shared__ float key[128];
    __shared__ float csum[128];
    __shared__ int   idxs[128];
    __shared__ int   rankv[128];

    const int tid  = threadIdx.x;
    const int w    = tid >> 6;       // wave 0..7
    const int l    = tid & 63;       // lane
    const int cw   = l >> 2;         // column slot 0..15
    const int s4   = l & 3;          // sub-lane in column
    const int k0   = s4 * 32;        // element range [k0, k0+32)
    const int col8 = cw & 7;
    const int half = cw >> 3;        // 0 = T half-block, 1 = B half-block
    const int m    = blockIdx.x;
    const int bb   = m / F_;
    const int ff   = m % F_;
    // initial global column: T = HB[w] (cols w*8..), B = HB[8+w] (cols 64+w*8..)
    const int gcol = half ? (64 + w * 8 + col8) : (w * 8 + col8);

    float G[32];
    #pragma unroll
    for (int i = 0; i < 32; ++i) G[i] = (k0 + i == gcol) ? MU : 0.f;

    // ---- Gram: G[k] = sum_j A[j][k]*A[j][gcol] (+MU on diagonal), 4 chunks
    {
        const float* Ab = Ain + (size_t)bb * 128 * 128 * F_ + ff;
        for (int c0 = 0; c0 < 128; c0 += 32) {
            for (int t = tid; t < 32 * 128; t += 512)
                SH[t] = Ab[(size_t)((c0 + (t >> 7)) * 128 + (t & 127)) * F_];
            __syncthreads();
            for (int j = 0; j < 32; ++j) {
                const float ac = SH[j * 128 + gcol];
                #pragma unroll
                for (int t = 0; t < 8; ++t) {
                    const float4 a = *(const float4*)&SH[j * 128 + k0 + 4 * t];
                    G[4*t+0] = fmaf(a.x, ac, G[4*t+0]);
                    G[4*t+1] = fmaf(a.y, ac, G[4*t+1]);
                    G[4*t+2] = fmaf(a.z, ac, G[4*t+2]);
                    G[4*t+3] = fmaf(a.w, ac, G[4*t+3]);
                }
            }
            __syncthreads();
        }
    }

    float pp = normsq(G);

    for (int sw = 0; sw < NSWEEP; ++sw) {
        // ---- intra-wave XOR tournament: all 120 pairs within the 16 cols
        for (int r = 1; r <= 15; ++r)
            jrot(G, pp, l ^ (r << 2), cw < (cw ^ r));

        // ---- 15 block-rounds: cross pairs between the two half-blocks
        for (int j = 0; j < 15; ++j) {
            for (int i = 0; i < 8; ++i) {
                int pslot;
                if (half == 0) pslot = 8 + ((cw + i) & 7);
                else           pslot = (cw - 8 - i) & 7;
                jrot(G, pp, (pslot << 2) | s4, half == 0);
            }
            // movement: 15-cycle on half-blocks (t0 fixed):
            // t1->t2->..->t7->b7->b6->..->b0->t1
            float* dst = nullptr;
            if (half == 0) {
                if (w >= 1 && w <= 6) dst = SH + (((w + 1) * 8 + col8) << 7) + k0;          // XT[w+1]
                else if (w == 7)      dst = SH + 8192 + ((7 * 8 + col8) << 7) + k0;         // XB[7]
            } else {
                if (w == 0)           dst = SH + ((1 * 8 + col8) << 7) + k0;                // XT[1]
                else                  dst = SH + 8192 + (((w - 1) * 8 + col8) << 7) + k0;   // XB[w-1]
            }
            if (dst) {
                #pragma unroll
                for (int t = 0; t < 8; ++t)
                    *(float4*)(dst + 4 * t) =
                        make_float4(G[4*t], G[4*t+1], G[4*t+2], G[4*t+3]);
            }
            __syncthreads();
            const float* src = nullptr;
            if (half == 0) { if (w >= 1) src = SH + ((w * 8 + col8) << 7) + k0; }           // XT[w]
            else                         src = SH + 8192 + ((w * 8 + col8) << 7) + k0;      // XB[w]
            if (src) {
                #pragma unroll
                for (int t = 0; t < 8; ++t) {
                    const float4 v = *(const float4*)(src + 4 * t);
                    G[4*t] = v.x; G[4*t+1] = v.y; G[4*t+2] = v.z; G[4*t+3] = v.w;
                }
            }
            __syncthreads();
            pp = normsq(G);
        }
        // after 15 movements the half-blocks are back at their initial waves
    }

    // ---- epilogue: exact norms -> eigenvalues; colsums; sort; V (transposed)
    float nrm = 0.f, cs = 0.f;
    #pragma unroll
    for (int i = 0; i < 32; ++i) { nrm = fmaf(G[i], G[i], nrm); cs += G[i]; }
    nrm = quad_reduce(nrm); cs = quad_reduce(cs);
    const float inv = 1.f / sqrtf(nrm);
    if (s4 == 0) {
        key[gcol]  = nrm;
        csum[gcol] = cs * inv * (1.f / 128.f);
    }
    __syncthreads();
    if (tid < 128) idxs[tid] = tid;
    __syncthreads();
    for (int kk = 2; kk <= 128; kk <<= 1) {
        for (int jj = kk >> 1; jj > 0; jj >>= 1) {
            if (tid < 128) {
                const int i = tid, l2 = i ^ jj;
                if (l2 > i) {
                    const bool up = ((i & kk) == 0);
                    const float ki = key[i], kl = key[l2];
                    if ((ki > kl) == up) {
                        const int ii = idxs[i], il = idxs[l2];
                        key[i] = kl; key[l2] = ki;
                        idxs[i] = il; idxs[l2] = ii;
                    }
                }
            }
            __syncthreads();
        }
    }
    if (tid < 128) rankv[idxs[tid]] = tid;
    __syncthreads();
    if (tid < 128) {
        e_out[(size_t)m * 128 + tid] = sqrtf(key[tid]) - MU;
        s_out[(size_t)m * 128 + tid] = csum[idxs[tid]];
    }
    {
        const int rk = rankv[gcol];
        __half* Vb = V_out + (size_t)m * 16384 + rk * 128 + k0;
        #pragma unroll
        for (int t = 0; t < 8; ++t) {
            __half2 h0 = __floats2half2_rn(G[4*t+0] * inv, G[4*t+1] * inv);
            __half2 h1 = __floats2half2_rn(G[4*t+2] * inv, G[4*t+3] * inv);
            float2 f;
            f.x = __uint_as_float(*reinterpret_cast<unsigned int*>(&h0));
            f.y = __uint_as_float(*reinterpret_cast<unsigned int*>(&h1));
            *(float2*)(Vb + 4 * t) = f;
        }
    }
}

// ---------------- Kernel 2: MLP on eigenvalues (128 -> 100 -> 100) --------
__global__ __launch_bounds__(128)
void mlp_kernel(const float* __restrict__ e_in,   // [BF][128]
                const float* __restrict__ W0,     // [128][100]
                const float* __restrict__ b0,
                const float* __restrict__ W1,     // [100][100]
                const float* __restrict__ b1,
                float* __restrict__ y_out)        // [BF][100]
{
    __shared__ float ein[128];
    __shared__ float h0[HID];
    const int m = blockIdx.x;
    const int tid = threadIdx.x;
    ein[tid] = e_in[(size_t)m * 128 + tid];
    __syncthreads();
    if (tid < HID) {
        float a = b0[tid];
        for (int i = 0; i < 128; ++i) a += ein[i] * W0[i * HID + tid];
        h0[tid] = fmaxf(a, 0.f);
    }
    __syncthreads();
    if (tid < HID) {
        float a = b1[tid];
        for (int h = 0; h < HID; ++h) a += h0[h] * W1[h * HID + tid];
        y_out[(size_t)m * HID + tid] = fmaxf(a, 0.f);
    }
}

// ---------------- Kernel 3: D = Ysub@W2blk + b2; Out = (D*s)@V^T; exp -----
__global__ __launch_bounds__(256)
void final_kernel(const float* __restrict__ y,     // [BF][100]
                  const float* __restrict__ W2,    // [100][16384]
                  const float* __restrict__ b2,    // [16384]
                  const float* __restrict__ s_in,  // [BF][128]
                  const __half* __restrict__ V_in, // [BF][128 cols][128 k] transposed
                  float* __restrict__ outp)        // [BF][128][128]
{
    extern __shared__ float lds[];
    float* Vs  = lds;            // [128][129] Vs[k][col] (filled in phase 2)
    float* Wm  = lds + 16512;    // [128][129]
    float* Ys  = lds;            // [128][101] staging (overlaps Vs)
    float* W2s = lds + 12928;    // [100][128] staging (overlaps Vs/Wm)

    const int m    = blockIdx.x;
    const int m_hi = m >> 7, m_lo = m & 127;
    const int tid  = threadIdx.x;
    const int tx   = tid & 15, ty = tid >> 4;

    for (int u = tid; u < 128 * 100; u += 256) {
        const int t = u / 100, h = u - t * 100;
        Ys[t * 101 + h] = y[(size_t)(5 * t + m_hi) * 100 + h];
    }
    for (int u = tid; u < 100 * 128; u += 256) {
        const int h = u >> 7, c = u & 127;
        W2s[h * 128 + c] = W2[(size_t)h * 16384 + (size_t)m_lo * 128 + c];
    }
    __syncthreads();

    float acc[8][8];
    #pragma unroll
    for (int a = 0; a < 8; ++a)
        #pragma unroll
        for (int c = 0; c < 8; ++c) acc[a][c] = 0.f;
    for (int h = 0; h < 100; ++h) {
        float yv[8], wv[8];
        #pragma unroll
        for (int a = 0; a < 8; ++a) yv[a] = Ys[(ty + 16 * a) * 101 + h];
        #pragma unroll
        for (int c = 0; c < 8; ++c) wv[c] = W2s[h * 128 + tx + 16 * c];
        #pragma unroll
        for (int a = 0; a < 8; ++a)
            #pragma unroll
            for (int c = 0; c < 8; ++c) acc[a][c] += yv[a] * wv[c];
    }
    {
        float b2v[8], sv[8];
        #pragma unroll
        for (int c = 0; c < 8; ++c) {
            b2v[c] = b2[m_lo * 128 + tx + 16 * c];
            sv[c]  = s_in[(size_t)m * 128 + tx + 16 * c];
        }
        #pragma unroll
        for (int a = 0; a < 8; ++a)
            #pragma unroll
            for (int c = 0; c < 8; ++c)
                acc[a][c] = (acc[a][c] + b2v[c]) * sv[c];
    }
    __syncthreads();

    #pragma unroll
    for (int a = 0; a < 8; ++a)
        #pragma unroll
        for (int c = 0; c < 8; ++c)
            Wm[(ty + 16 * a) * 129 + tx + 16 * c] = acc[a][c];
    for (int u = tid; u < 16384; u += 256) {
        const int colj = u >> 7, k = u & 127;
        Vs[k * 129 + colj] = __half2float(V_in[(size_t)m * 16384 + u]);
    }
    __syncthreads();

    float o[8][8];
    #pragma unroll
    for (int a = 0; a < 8; ++a)
        #pragma unroll
        for (int c = 0; c < 8; ++c) o[a][c] = 0.f;
    for (int j = 0; j < 128; ++j) {
        float wv[8], vv[8];
        #pragma unroll
        for (int a = 0; a < 8; ++a) wv[a] = Wm[(ty + 16 * a) * 129 + j];
        #pragma unroll
        for (int c = 0; c < 8; ++c) vv[c] = Vs[(tx + 16 * c) * 129 + j];
        #pragma unroll
        for (int a = 0; a < 8; ++a)
            #pragma unroll
            for (int c = 0; c < 8; ++c) o[a][c] += wv[a] * vv[c];
    }
    #pragma unroll
    for (int a = 0; a < 8; ++a) {
        const int t = ty + 16 * a;
        const size_t rowbase = (size_t)(5 * t + m_hi) * 16384 + (size_t)m_lo * 128;
        #pragma unroll
        for (int c = 0; c < 8; ++c)
            outp[rowbase + tx + 16 * c] = expf(o[a][c]);
    }
}

// ---------------------------------------------------------------------------
extern "C" void kernel_launch(void* const* d_in, const int* in_sizes, int n_in,
                              void* d_out, int out_size, void* d_ws, size_t ws_size,
                              hipStream_t stream)
{
    const float* Ain = (const float*)d_in[0];
    const float* W0  = (const float*)d_in[1];
    const float* b0  = (const float*)d_in[2];
    const float* W1  = (const float*)d_in[3];
    const float* b1  = (const float*)d_in[4];
    const float* W2  = (const float*)d_in[5];
    const float* b2  = (const float*)d_in[6];
    float* outp = (float*)d_out;

    char* ws = (char*)d_ws;
    __half* Vh  = (__half*)ws;                               // 640*16384*2 = 20971520 B
    float* e_ws = (float*)(ws + 20971520);                   // 640*128*4
    float* s_ws = (float*)(ws + 20971520 + 327680);          // 640*128*4
    float* y_ws = (float*)(ws + 20971520 + 655360);          // 640*100*4

    const size_t lds_bytes = (size_t)(2 * 128 * 129) * sizeof(float); // 132096

    eig_kernel<<<dim3(BF), dim3(512), 0, stream>>>(Ain, e_ws, s_ws, Vh);
    mlp_kernel<<<dim3(BF), dim3(128), 0, stream>>>(e_ws, W0, b0, W1, b1, y_ws);
    final_kernel<<<dim3(BF), dim3(256), lds_bytes, stream>>>(y_ws, W2, b2, s_ws, Vh, outp);
}